// Round 14
// baseline (104.215 us; speedup 1.0000x reference)
//
#include <hip/hip_runtime.h>
#include <math.h>

#define A_W 0.955f
#define B_W 1.3693f
#define INF_W 1e6f
#define HDIM 512
#define WDIM 512
#define NPIX (HDIM*WDIM)
#define NSAMP 16
#define NTOT_F 4194304.0f
#define TST 4        // strip height
#define NSTRIP 128   // strips per sample
#define NBLK (NSAMP*NSTRIP)        // 2048
#define STRIP_COST (4.0f * A_W)    // min cost to propagate a boundary through one strip

// ws layout (bytes):
//  [0,8192):        int f1[2048]    (phase-1 done flags, per strip)       [cleared]
//  [8192,16384):    int f2[2048]    (phase-2 done flags, per flipped strip)[cleared]
//  [16384,24576):   int f3[2048]    (phase-3 done flags)                  [cleared]
//  [24576,24704):   int f4[16]+pad  (per-sample phase-4a done flags)      [cleared]
//  [32768,81920):   float sacc[6][2048]
//  [81920,90112):   float mmax1[2048]   (max of Llast rows)
//  [90112,98304):   float mmax2[2048]   (max of Llast2 rows)
//  [98304,106496):  int blkflags[2048]  (bit0=has_fg,bit1=has_bg; fully rewritten)
//  [106496,106880): float sacc2[6][16]  (per-sample partials)
//  [106880,106944): int vv2[16]         (per-sample blkflag OR)
//  [1MB,5MB):       float Llast[16][128][512]
//  [5MB,9MB):       float Llast2[16][128][512]
#define OFF_F1     0
#define OFF_F2     8192
#define OFF_F3     16384
#define OFF_F4     24576
#define OFF_SACC   32768
#define OFF_MMAX1  81920
#define OFF_MMAX2  90112
#define OFF_FLAGS  98304
#define OFF_SACC2  106496
#define OFF_VV2    106880
#define OFF_LLAST  (1u<<20)
#define OFF_LLAST2 (5u<<20)

typedef float f32x4 __attribute__((ext_vector_type(4)));

// ---- fence-free cross-block data movement --------------------------------------
// gfx950 XCD L2s are non-coherent; agent-scope ACQ/REL atomics emit whole-L2
// writeback/invalidate (round 4: ~420us floor). Proven scheme (rounds 5/6/8/10-12):
// payload via L1+L2-BYPASS ops (-> MALL, common point); producer drains with
// s_waitcnt vmcnt(0); SIGNAL = RELAXED ATOMIC RMW on a distinct per-strip flag
// (plain-store signal broke visibility in round 7; hot-line RMWs serialized in
// round 6 — known regressions, do not revisit).
// ROUND-9 MECHANISM (attributed via round 12): compiler-tracked loads left
// outstanding ACROSS inline-asm vmem ops get consumed early — the compiler's
// counted vmcnt(N) doesn't include asm loads. RULE: any compiler-tracked global
// load must be issued AND consumed with no intervening inline-asm vmem.
// ROUND-14 = round-13 retry (infra failure): phase-1 tg rows batch-issued
// (12 uint4 in flight) before processing — issue->use window contains no asm
// vmem (chain_walk is phase 2), so the counted-wait invariant holds.
__device__ __forceinline__ void st_wti(int* p, int v) {
    __hip_atomic_store(p, v, __ATOMIC_RELAXED, __HIP_MEMORY_SCOPE_AGENT);
}
__device__ __forceinline__ int ld_bpi(const int* p) {
    return __hip_atomic_load((int*)p, __ATOMIC_RELAXED, __HIP_MEMORY_SCOPE_AGENT);
}
__device__ __forceinline__ void st_wt(float* p, float v) {
    st_wti((int*)p, __float_as_int(v));
}
__device__ __forceinline__ float ld_bp(const float* p) {
    return __int_as_float(ld_bpi((const int*)p));
}
// 16B-wide L1+L2-bypass ops. "=&v" early-clobber: dest must not overlap the
// address pair. Results readable only after vm_wait0().
__device__ __forceinline__ f32x4 ld_bp4(const float* p) {
    f32x4 r;
    asm volatile("global_load_dwordx4 %0, %1, off sc0 sc1"
                 : "=&v"(r) : "v"(p) : "memory");
    return r;
}
__device__ __forceinline__ void st_wt4(float* p, f32x4 v) {
    asm volatile("global_store_dwordx4 %0, %1, off sc0 sc1"
                 :: "v"(p), "v"(v) : "memory");
}
__device__ __forceinline__ void vm_wait0() {
    asm volatile("s_waitcnt vmcnt(0)" ::: "memory");
    __builtin_amdgcn_sched_barrier(0);   // block reg-only hoisting past the wait
}
// async global->LDS DMA, 16B per lane: LDS dest = lp + lane*16, global src = gp
// (per-lane). Compiler-tracked (vmcnt); any vmcnt(0) drain covers it.
__device__ __forceinline__ void gll16(const float* gp, float* lp) {
    __builtin_amdgcn_global_load_lds(
        (const __attribute__((address_space(1))) void*)gp,
        (__attribute__((address_space(3))) void*)lp, 16, 0, 0);
}

// Publish: drain this wave's write-through stores to MALL (vmcnt is wave-level,
// covers all 64 lanes), then bump the flag with a relaxed RMW.
__device__ __forceinline__ void flag_post(int* f, int lane) {
    asm volatile("s_waitcnt vmcnt(0)" ::: "memory");
    if (lane == 0)
        __hip_atomic_fetch_add(f, 1, __ATOMIC_RELAXED, __HIP_MEMORY_SCOPE_AGENT);
}
__device__ __forceinline__ void wait_flag(const int* f) {
    while (!__all(ld_bpi(f) != 0))
        __builtin_amdgcn_s_sleep(2);
    asm volatile("" ::: "memory");   // no payload reads hoisted above the spin
}
// wait until f[k] != 0 for all k in [k0, kend); kend-k0 <= 128
__device__ __forceinline__ void wait_flags_range(const int* f, int k0, int kend,
                                                 int lane) {
    if (k0 >= kend) return;
    for (;;) {
        int k1 = k0 + lane, k2 = k0 + 64 + lane;
        int v1 = (k1 < kend) ? ld_bpi(&f[k1]) : 1;
        int v2 = (k2 < kend) ? ld_bpi(&f[k2]) : 1;
        if (__all((v1 != 0) & (v2 != 0))) break;
        __builtin_amdgcn_s_sleep(2);
    }
    asm volatile("" ::: "memory");
}

// DPP move with INF fill (floats).
template<int CTRL, int RMASK>
__device__ __forceinline__ float dpp_mov_inf(float x) {
    return __int_as_float(__builtin_amdgcn_update_dpp(
        __float_as_int(INF_W), __float_as_int(x), CTRL, RMASK, 0xF, false));
}
template<int CTRL>
__device__ __forceinline__ int dpp_mov0_i(int x) {
    return __builtin_amdgcn_update_dpp(0, x, CTRL, 0xF, 0xF, true);
}

__device__ __forceinline__ float wave_prefix_min_incl(float t) {
    t = fminf(t, dpp_mov_inf<0x111,0xF>(t));
    t = fminf(t, dpp_mov_inf<0x112,0xF>(t));
    t = fminf(t, dpp_mov_inf<0x114,0xF>(t));
    t = fminf(t, dpp_mov_inf<0x118,0xF>(t));
    t = fminf(t, dpp_mov_inf<0x142,0xA>(t));
    t = fminf(t, dpp_mov_inf<0x143,0xC>(t));
    return t;
}

__device__ __forceinline__ void cummin_row(const float* jc, float* v) {
    float g[8];
#pragma unroll
    for (int i = 0; i < 8; ++i) g[i] = v[i] - jc[i];
    float c1[8];
    c1[0] = g[0];
#pragma unroll
    for (int i = 1; i < 8; ++i) c1[i] = fminf(g[i], g[i-1]);
    float c2[8];
    c2[0] = c1[0]; c2[1] = c1[1];
#pragma unroll
    for (int i = 2; i < 8; ++i) c2[i] = fminf(c1[i], c1[i-2]);
    float cj[8];
    cj[0] = c2[0]; cj[1] = c2[1]; cj[2] = c2[2]; cj[3] = c2[3];
#pragma unroll
    for (int i = 4; i < 8; ++i) cj[i] = fminf(c2[i], c2[i-4]);
    float t  = wave_prefix_min_incl(cj[7]);
    float ex = dpp_mov_inf<0x138,0xF>(t);
#pragma unroll
    for (int i = 0; i < 8; ++i) v[i] = jc[i] + fminf(cj[i], ex);
}

__device__ __forceinline__ void row_step(const float* jc, float* prev, const float* drow) {
    float lIn = dpp_mov_inf<0x138,0xF>(prev[7]);
    float rIn = dpp_mov_inf<0x130,0xF>(prev[0]);
    float m[8];
#pragma unroll
    for (int i = 0; i < 8; ++i) {
        float up = prev[i] + A_W;
        float ul = ((i == 0) ? lIn : prev[i-1]) + B_W;
        float ur = ((i == 7) ? rIn : prev[i+1]) + B_W;
        m[i] = fminf(fminf(drow[i], up), fminf(ul, ur));
    }
    cummin_row(jc, m);
#pragma unroll
    for (int i = 0; i < 8; ++i) prev[i] = m[i];
}

// 4 fused T3 steps (exact, INF outside grid). T3^4 == one call (TST==4).
__device__ __forceinline__ void t3x4(float* b) {
    float e[16];
#pragma unroll
    for (int k = 0; k < 4; ++k) e[k]    = dpp_mov_inf<0x138,0xF>(b[4+k]);
#pragma unroll
    for (int k = 0; k < 8; ++k) e[4+k]  = b[k];
#pragma unroll
    for (int k = 0; k < 4; ++k) e[12+k] = dpp_mov_inf<0x130,0xF>(b[k]);
    const float w0 = 4.f*A_W, w1 = 3.f*A_W + B_W, w2 = 2.f*A_W + 2.f*B_W;
    const float w3 = A_W + 3.f*B_W, w4 = 4.f*B_W;
#pragma unroll
    for (int i = 0; i < 8; ++i) {
        float m = e[i+4] + w0;
        m = fminf(m, fminf(e[i+3], e[i+5]) + w1);
        m = fminf(m, fminf(e[i+2], e[i+6]) + w2);
        m = fminf(m, fminf(e[i+1], e[i+7]) + w3);
        m = fminf(m, fminf(e[i+0], e[i+8]) + w4);
        b[i] = m;
    }
}

struct RowBits { int efg; int ebg; int rawbg; };

__device__ __forceinline__ RowBits make_rowbits(uint4 a, uint4 b) {
    int fg = ((a.x!=0u)?1:0) | ((a.y!=0u)?2:0) | ((a.z!=0u)?4:0) | ((a.w!=0u)?8:0)
           | ((b.x!=0u)?16:0) | ((b.y!=0u)?32:0) | ((b.z!=0u)?64:0) | ((b.w!=0u)?128:0);
    int bg = (~fg) & 0xFF;
    int lf = dpp_mov0_i<0x138>(fg), rf = dpp_mov0_i<0x130>(fg);
    int lb = dpp_mov0_i<0x138>(bg), rb = dpp_mov0_i<0x130>(bg);
    RowBits r;
    r.efg = (fg | (fg<<1) | (fg>>1) | ((lf>>7)&1) | ((rf&1)<<7)) & 0xFF;
    r.ebg = (bg | (bg<<1) | (bg>>1) | ((lb>>7)&1) | ((rb&1)<<7)) & 0xFF;
    r.rawbg = bg;
    return r;
}

// store max of an L row (prev[8] across wave) into mmax (write-through)
__device__ __forceinline__ void store_max(const float* prev, float* __restrict__ mmax,
                                          int idx, int lane) {
    float mx = prev[0];
#pragma unroll
    for (int i = 1; i < 8; ++i) mx = fmaxf(mx, prev[i]);
#pragma unroll
    for (int off = 32; off > 0; off >>= 1) mx = fmaxf(mx, __shfl_xor(mx, off));
    if (lane == 0) st_wt(&mmax[idx], mx);
}

// Exact boundary via chain walk over strips [k0, n-1]. Caller guarantees flags
// [k0, n-1] observed. 16B bypass loads issued before t3x4/cummin to hide MALL
// latency; results consumed only after vm_wait0().
__device__ __forceinline__ void chain_walk(const float* __restrict__ Lb, int k0, int n,
                                           const float* jc, int c0, float* prev) {
    float b[8];
    const float* Lr = Lb + (size_t)k0 * WDIM + c0;
    f32x4 l0 = ld_bp4(Lr);
    f32x4 l1 = ld_bp4(Lr + 4);
    vm_wait0();
#pragma unroll
    for (int i = 0; i < 4; ++i) { b[i] = l0[i]; b[4 + i] = l1[i]; }
    for (int sg = k0 + 1; sg < n; ++sg) {
        const float* Ls = Lb + (size_t)sg * WDIM + c0;
        f32x4 m0 = ld_bp4(Ls);
        f32x4 m1 = ld_bp4(Ls + 4);
        t3x4(b);                                 // T3^4 exact (TST==4)
        cummin_row(jc, b);
        vm_wait0();
#pragma unroll
        for (int i = 0; i < 4; ++i) {
            b[i]     = fminf(b[i],     m0[i]);
            b[4 + i] = fminf(b[4 + i], m1[i]);
        }
    }
#pragma unroll
    for (int i = 0; i < 8; ++i) prev[i] = b[i];
}

// k0 from ub = maxL[n-1]: keep strips with STRIP_COST*(n-1-k) <= ub (distances
// >= 0 make this sufficient; 1e-3 margin => rounding can only KEEP extra strips,
// never drop a tied one -> exact). g clamped to [0,127] defensively.
__device__ __forceinline__ int k0_from_ub(float ub, int n) {
    int g = (int)(ub * (1.0f / STRIP_COST) + 1e-3f);
    if (g < 0) g = 0;
    if (g > NSTRIP - 1) g = NSTRIP - 1;
    int k0 = n - 1 - g;
    return (k0 < 0) ? 0 : k0;
}

// =====================================================================================
// Fused kernel: all 3 strip phases + two-level final reduce in ONE dispatch.
// Co-residency by construction: __launch_bounds__(64,2) caps VGPR at 256 (>=2
// waves/SIMD -> >=8 blocks/CU); LDS 16KB -> 10 blocks/CU; min=10 blocks/CU x 256
// CU = 2560 slots >= 2048 blocks => waits cannot deadlock (deps form a DAG).
// (64,4) forbidden: VGPR->64, ~90MB scratch spill (round 3).
// This round (retry of round 13, ONE change): phase-1 tg rows batch-issued
// (12 uint4 = 192B/lane in flight) before any bit processing — MLP for the
// cold-HBM tg fetch (~17us of the ~35us kernel at latency-bound ~960GB/s).
// =====================================================================================
__global__ __launch_bounds__(64, 2) void fused_kernel(
        const float* __restrict__ pred, const int* __restrict__ tg,
        const float* __restrict__ lv, float* __restrict__ out,
        float* __restrict__ Llast, float* __restrict__ mmax1, int* __restrict__ blkflags,
        float* __restrict__ Llast2, float* __restrict__ mmax2, float* __restrict__ sacc,
        int* f1, int* f2, int* f3, int* f4,
        float* __restrict__ sacc2, int* __restrict__ vv2) {
    const int s = blockIdx.x >> 7, sig = blockIdx.x & 127;
    const int lane = threadIdx.x;
    const int c0 = lane * 8;
    const int* tgb = tg + (size_t)s * NPIX;
    const int R0 = sig * TST;
    const int base = s * NSTRIP;
    float jc[8];
#pragma unroll
    for (int i = 0; i < 8; ++i) jc[i] = A_W * (float)(c0 + i);

    __shared__ float lds[TST][WDIM];      // 8 KB: pass-1 rows for phases 2/3
    __shared__ float predlds[TST][WDIM];  // 8 KB: pred rows (DMA'd at entry)

    // ---------------- phase 1: local strip scan (INF incoming) -> Llast/mmax1/flags
    // Batch-issue ALL 6 tg rows (12 x uint4 = 192B/lane in flight) before any
    // processing — MLP for the cold-HBM fetch. OOB rows: clamped (safe) address,
    // bits zeroed afterwards (semantics identical to the guarded loader).
    // Issue->use window contains NO inline-asm vmem (round-9 rule holds).
    uint4 ta[TST + 2], tb[TST + 2];
#pragma unroll
    for (int r = 0; r < TST + 2; ++r) {
        int rr = R0 - 1 + r;
        int rrc = rr < 0 ? 0 : (rr >= HDIM ? HDIM - 1 : rr);
        const uint4* p = (const uint4*)(tgb + (size_t)rrc * WDIM + c0);
        ta[r] = p[0];
        tb[r] = p[1];
    }
    // pred DMA issued AFTER the tg batch: the compiler's counted wait for tg can
    // leave the 8 DMAs outstanding; phase-1's flag_post vmcnt(0) drains them.
    {
        const float* pb = pred + (size_t)s * NPIX + (size_t)R0 * WDIM;
#pragma unroll
        for (int tt = 0; tt < TST; ++tt) {
#pragma unroll
            for (int h = 0; h < 2; ++h) {
                gll16(pb + (size_t)tt * WDIM + h * 256 + lane * 4,
                      &predlds[tt][h * 256]);
            }
        }
    }
    RowBits rbv[TST + 2];
#pragma unroll
    for (int r = 0; r < TST + 2; ++r) {
        int rr = R0 - 1 + r;
        if (rr < 0 || rr >= HDIM) {
            rbv[r].efg = 0; rbv[r].ebg = 0; rbv[r].rawbg = 0;
        } else {
            rbv[r] = make_rowbits(ta[r], tb[r]);
        }
    }
    unsigned int smaskp = 0u, rawbgp = 0u;   // byte t = row t's 8-bit masks
    float prev[8];
#pragma unroll
    for (int i = 0; i < 8; ++i) prev[i] = INF_W;
    int fgor = 0, bgor = 0;
#pragma unroll
    for (int t = 0; t < TST; ++t) {
        fgor |= (~rbv[t + 1].rawbg) & 0xFF;
        bgor |= rbv[t + 1].rawbg;
        int smask = (rbv[t].efg | rbv[t + 1].efg | rbv[t + 2].efg)
                  & (rbv[t].ebg | rbv[t + 1].ebg | rbv[t + 2].ebg);
        smaskp |= ((unsigned int)smask) << (8 * t);
        rawbgp |= ((unsigned int)rbv[t + 1].rawbg) << (8 * t);
        float dr[8];
#pragma unroll
        for (int i = 0; i < 8; ++i) dr[i] = ((smask >> i) & 1) ? 0.f : INF_W;
        row_step(jc, prev, dr);
    }
    {
        float* Lr = Llast + ((size_t)base + sig) * WDIM + c0;
        f32x4 v0 = {prev[0], prev[1], prev[2], prev[3]};
        f32x4 v1 = {prev[4], prev[5], prev[6], prev[7]};
        st_wt4(Lr, v0);
        st_wt4(Lr + 4, v1);
        store_max(prev, mmax1, base + sig, lane);
        int wf = __any(fgor != 0) ? 1 : 0;
        int wb = __any(bgor != 0) ? 2 : 0;
        if (lane == 0) st_wti(&blkflags[blockIdx.x], wf | wb);
    }
    flag_post(&f1[base + sig], lane);   // vmcnt(0) here also drains the pred DMA

    // ---------------- phase 2: exact pass-1 rows -> LDS; flipped local scan -> Llast2/mmax2
    if (sig == 0) {
#pragma unroll
        for (int i = 0; i < 8; ++i) prev[i] = INF_W;
    } else {
        wait_flag(&f1[base + sig - 1]);
        float ub = ld_bp(&mmax1[base + sig - 1]);
        int k0 = k0_from_ub(ub, sig);
        wait_flags_range(f1 + base, k0, sig - 1, lane);
        chain_walk(Llast + (size_t)base * WDIM, k0, sig, jc, c0, prev);
    }
#pragma unroll
    for (int t = 0; t < TST; ++t) {
        unsigned int sm = (smaskp >> (8 * t)) & 0xFFu;
        float dr[8];
#pragma unroll
        for (int i = 0; i < 8; ++i) dr[i] = ((sm >> i) & 1u) ? 0.f : INF_W;
        row_step(jc, prev, dr);
        *(float4*)&lds[t][c0]     = make_float4(prev[0], prev[1], prev[2], prev[3]);
        *(float4*)&lds[t][c0 + 4] = make_float4(prev[4], prev[5], prev[6], prev[7]);
    }
    __syncthreads();
    // flipped (pass-2) local scan over this strip, INF incoming
#pragma unroll
    for (int i = 0; i < 8; ++i) prev[i] = INF_W;
#pragma unroll
    for (int t2 = 0; t2 < TST; ++t2) {
        float4 a = *(const float4*)&lds[TST - 1 - t2][504 - c0];
        float4 q = *(const float4*)&lds[TST - 1 - t2][508 - c0];
        float dr[8];
        dr[7]=a.x; dr[6]=a.y; dr[5]=a.z; dr[4]=a.w;
        dr[3]=q.x; dr[2]=q.y; dr[1]=q.z; dr[0]=q.w;
        row_step(jc, prev, dr);
    }
    const int sig2 = NSTRIP - 1 - sig;   // flipped strip index == this block's own rows
    {
        float* Lr = Llast2 + ((size_t)base + sig2) * WDIM + c0;
        f32x4 v0 = {prev[0], prev[1], prev[2], prev[3]};
        f32x4 v1 = {prev[4], prev[5], prev[6], prev[7]};
        st_wt4(Lr, v0);
        st_wt4(Lr + 4, v1);
        store_max(prev, mmax2, base + sig2, lane);
    }
    flag_post(&f2[base + sig2], lane);

    // ---------------- phase 3: exact pass-2 rows (dr from own LDS) + fused loss -> sacc
    if (sig2 == 0) {
#pragma unroll
        for (int i = 0; i < 8; ++i) prev[i] = INF_W;
    } else {
        wait_flag(&f2[base + sig2 - 1]);
        float ub = ld_bp(&mmax2[base + sig2 - 1]);
        int k0 = k0_from_ub(ub, sig2);
        wait_flags_range(f2 + base, k0, sig2 - 1, lane);
        chain_walk(Llast2 + (size_t)base * WDIM, k0, sig2, jc, c0, prev);
    }
    float mx = 0.f, facc = 0.f, s1 = 0.f, s2 = 0.f, iacc = 0.f, pacc = 0.f;
#pragma unroll
    for (int t = 0; t < TST; ++t) {
        float4 a  = *(const float4*)&lds[TST - 1 - t][504 - c0];
        float4 b4 = *(const float4*)&lds[TST - 1 - t][508 - c0];
        float dr[8];
        dr[7]=a.x;  dr[6]=a.y;  dr[5]=a.z;  dr[4]=a.w;
        dr[3]=b4.x; dr[2]=b4.y; dr[1]=b4.z; dr[0]=b4.w;
        // pred row pr = R0 + (TST-1-t): predlds row index == TST-1-t; same
        // reversed-float4 pattern as the dr reads above.
        float4 xa = *(const float4*)&predlds[TST - 1 - t][504 - c0];
        float4 xb = *(const float4*)&predlds[TST - 1 - t][508 - c0];
        float px[8];
        px[7]=xa.x; px[6]=xa.y; px[5]=xa.z; px[4]=xa.w;
        px[3]=xb.x; px[2]=xb.y; px[1]=xb.z; px[0]=xb.w;
        // target bits for reversed columns: col 511-c0-i lives in lane 63-lane, bit 7-i
        int sh = __shfl((int)((rawbgp >> (8 * (TST - 1 - t))) & 0xFFu), 63 - lane);
        row_step(jc, prev, dr);
#pragma unroll
        for (int i = 0; i < 8; ++i) {
            float x = px[i];
            float dd = prev[i];
            float e = __expf(-fabsf(x));
            float inv = 1.f / (1.f + e);
            float pr_ = (x >= 0.f) ? inv : (1.f - inv);   // sigmoid(x)
            float L = __logf(1.f + e);                    // softplus(-|x|)
            bool t1 = ((sh >> (7 - i)) & 1) == 0;         // fg pixel
            float fo = t1 ? 0.25f * (1.f - pr_) * (1.f - pr_) * (fmaxf(-x, 0.f) + L)
                          : 0.75f * pr_ * pr_ * (fmaxf(x, 0.f) + L);
            facc += fo;
            float base_ = t1 ? (1.f - pr_) : pr_;
            s1 += base_;
            s2 += base_ * dd;
            float tf = t1 ? 1.f : 0.f;
            iacc += tf * pr_;
            pacc += pr_ + tf;
            mx = fmaxf(mx, dd);
        }
    }
#pragma unroll
    for (int off = 32; off > 0; off >>= 1) {
        facc += __shfl_xor(facc, off);
        s1   += __shfl_xor(s1, off);
        s2   += __shfl_xor(s2, off);
        iacc += __shfl_xor(iacc, off);
        pacc += __shfl_xor(pacc, off);
        mx    = fmaxf(mx, __shfl_xor(mx, off));
    }
    if (lane == 0) {
        const int idx = base + sig2;
        st_wt(&sacc[0 * NBLK + idx], s1);
        st_wt(&sacc[1 * NBLK + idx], s2);
        st_wt(&sacc[2 * NBLK + idx], iacc);
        st_wt(&sacc[3 * NBLK + idx], pacc);
        st_wt(&sacc[4 * NBLK + idx], mx);
        st_wt(&sacc[5 * NBLK + idx], facc);
    }
    flag_post(&f3[blockIdx.x], lane);

    // ---------------- phase 4a: per-sample reduce in each sample's sig==0 block
    if (sig != 0) return;
    wait_flags_range(f3, base, base + NSTRIP, lane);
    {
        int i0 = base + lane, i1 = i0 + 64;
        float t1 = ld_bp(&sacc[0 * NBLK + i0]) + ld_bp(&sacc[0 * NBLK + i1]);
        float t2 = ld_bp(&sacc[1 * NBLK + i0]) + ld_bp(&sacc[1 * NBLK + i1]);
        float ia = ld_bp(&sacc[2 * NBLK + i0]) + ld_bp(&sacc[2 * NBLK + i1]);
        float pa = ld_bp(&sacc[3 * NBLK + i0]) + ld_bp(&sacc[3 * NBLK + i1]);
        float mxs = fmaxf(ld_bp(&sacc[4 * NBLK + i0]), ld_bp(&sacc[4 * NBLK + i1]));
        float fa = ld_bp(&sacc[5 * NBLK + i0]) + ld_bp(&sacc[5 * NBLK + i1]);
        int   vv = ld_bpi(&blkflags[i0]) | ld_bpi(&blkflags[i1]);
#pragma unroll
        for (int off = 32; off > 0; off >>= 1) {
            t1 += __shfl_xor(t1, off);
            t2 += __shfl_xor(t2, off);
            ia += __shfl_xor(ia, off);
            pa += __shfl_xor(pa, off);
            fa += __shfl_xor(fa, off);
            mxs = fmaxf(mxs, __shfl_xor(mxs, off));
            vv |= __shfl_xor(vv, off);
        }
        if (lane == 0) {
            st_wt(&sacc2[0 * 16 + s], t1);
            st_wt(&sacc2[1 * 16 + s], t2);
            st_wt(&sacc2[2 * 16 + s], ia);
            st_wt(&sacc2[3 * 16 + s], pa);
            st_wt(&sacc2[4 * 16 + s], mxs);
            st_wt(&sacc2[5 * 16 + s], fa);
            st_wti(&vv2[s], vv);
        }
    }
    flag_post(&f4[s], lane);

    // ---------------- phase 4b: final combine in block 0 (16 lane-parallel samples)
    if (blockIdx.x != 0) return;
    for (;;) {
        int v = (lane < NSAMP) ? ld_bpi(&f4[lane]) : 1;
        if (__all(v != 0)) break;
        __builtin_amdgcn_s_sleep(2);
    }
    asm volatile("" ::: "memory");
    float fsum = 0.f, bsum = 0.f, dsum = 0.f, isum = 0.f;
    if (lane < NSAMP) {
        float t1  = ld_bp(&sacc2[0 * 16 + lane]);
        float t2  = ld_bp(&sacc2[1 * 16 + lane]);
        float ia  = ld_bp(&sacc2[2 * 16 + lane]);
        float pa  = ld_bp(&sacc2[3 * 16 + lane]);
        float mxs = ld_bp(&sacc2[4 * 16 + lane]);
        float fa  = ld_bp(&sacc2[5 * 16 + lane]);
        int   vv  = ld_bpi(&vv2[lane]);
        bool hasb = (vv & 3) == 3;     // boundary nonempty (has_fg && has_bg)
        fsum = fa;
        float distsum = hasb ? ((mxs > 0.f) ? t2 / fmaxf(mxs, 1e-12f) : 0.f) : t1;
        bsum = t1 + distsum;
        dsum = (2.f * ia + 1e-6f) / (pa + 1e-6f);
        isum = (ia + 1e-6f) / (pa - ia + 1e-6f);
    }
#pragma unroll
    for (int off = 32; off > 0; off >>= 1) {
        fsum += __shfl_xor(fsum, off);
        bsum += __shfl_xor(bsum, off);
        dsum += __shfl_xor(dsum, off);
        isum += __shfl_xor(isum, off);
    }
    if (lane == 0) {
        float focal = fsum / NTOT_F;
        float bnd   = bsum / NTOT_F;
        float dice = 1.f - dsum / 16.f;
        float iou  = 1.f - isum / 16.f;
        float l0 = lv[0], l1 = lv[1], l2 = lv[2], l3 = lv[3];
        float total = expf(-l0) * focal + l0 + expf(-l1) * dice + l1
                    + expf(-l2) * bnd  + l2 + expf(-l3) * iou  + l3;
        out[0] = total; out[1] = focal; out[2] = dice; out[3] = bnd; out[4] = iou;
    }
}

extern "C" void kernel_launch(void* const* d_in, const int* in_sizes, int n_in,
                              void* d_out, int out_size, void* d_ws, size_t ws_size,
                              hipStream_t stream) {
    const float* pred = (const float*)d_in[0];
    const int*   tg   = (const int*)d_in[1];
    const float* lv   = (const float*)d_in[2];
    float* out = (float*)d_out;
    char* ws = (char*)d_ws;
    int*   f1       = (int*)(ws + OFF_F1);
    int*   f2       = (int*)(ws + OFF_F2);
    int*   f3       = (int*)(ws + OFF_F3);
    int*   f4       = (int*)(ws + OFF_F4);
    int*   blkflags = (int*)(ws + OFF_FLAGS);
    float* sacc     = (float*)(ws + OFF_SACC);
    float* mmax1    = (float*)(ws + OFF_MMAX1);
    float* mmax2    = (float*)(ws + OFF_MMAX2);
    float* sacc2    = (float*)(ws + OFF_SACC2);
    int*   vv2      = (int*)(ws + OFF_VV2);
    float* Llast    = (float*)(ws + OFF_LLAST);
    float* Llast2   = (float*)(ws + OFF_LLAST2);

    // ws is poisoned between iterations -> flags (f1,f2,f3,f4) must be zeroed.
    hipMemsetAsync(ws, 0, 24704, stream);
    fused_kernel<<<NBLK, 64, 0, stream>>>(pred, tg, lv, out, Llast, mmax1, blkflags,
                                          Llast2, mmax2, sacc, f1, f2, f3, f4,
                                          sacc2, vv2);
}

// Round 15
// 101.794 us; speedup vs baseline: 1.0238x; 1.0238x over previous
//
#include <hip/hip_runtime.h>
#include <math.h>

#define A_W 0.955f
#define B_W 1.3693f
#define INF_W 1e6f
#define HDIM 512
#define WDIM 512
#define NPIX (HDIM*WDIM)
#define NSAMP 16
#define NTOT_F 4194304.0f
#define TST 4        // strip height
#define NSTRIP 128   // strips per sample
#define NBLK (NSAMP*NSTRIP)        // 2048
#define STRIP_COST (4.0f * A_W)    // min cost to propagate a boundary through one strip

// ws layout (bytes):
//  [0,8192):        int f1[2048]    (phase-1 done flags, per strip)       [cleared]
//  [8192,16384):    int f2[2048]    (phase-2 done flags, per flipped strip)[cleared]
//  [16384,24576):   int f3[2048]    (phase-3 done flags)                  [cleared]
//  [24576,24704):   int f4[16]+pad  (per-sample phase-4a done flags)      [cleared]
//  [32768,81920):   float sacc[6][2048]
//  [81920,90112):   float mmax1[2048]   (max of Llast rows)
//  [90112,98304):   float mmax2[2048]   (max of Llast2 rows)
//  [98304,106496):  int blkflags[2048]  (bit0=has_fg,bit1=has_bg; fully rewritten)
//  [106496,106880): float sacc2[6][16]  (per-sample partials)
//  [106880,106944): int vv2[16]         (per-sample blkflag OR)
//  [1MB,5MB):       float Llast[16][128][512]
//  [5MB,9MB):       float Llast2[16][128][512]
#define OFF_F1     0
#define OFF_F2     8192
#define OFF_F3     16384
#define OFF_F4     24576
#define OFF_SACC   32768
#define OFF_MMAX1  81920
#define OFF_MMAX2  90112
#define OFF_FLAGS  98304
#define OFF_SACC2  106496
#define OFF_VV2    106880
#define OFF_LLAST  (1u<<20)
#define OFF_LLAST2 (5u<<20)

typedef float f32x4 __attribute__((ext_vector_type(4)));

// ---- fence-free cross-block data movement --------------------------------------
// gfx950 XCD L2s are non-coherent; agent-scope ACQ/REL atomics emit whole-L2
// writeback/invalidate (round 4: ~420us floor). Proven scheme (rounds 5/6/8/10/11):
// payload via L1+L2-BYPASS ops (-> MALL, common point); producer drains with
// s_waitcnt vmcnt(0); SIGNAL = RELAXED ATOMIC RMW on a distinct per-strip flag
// (plain-store signal broke visibility in round 7; hot-line RMWs serialized in
// round 6 — known regressions, do not revisit).
// SESSION VERDICT (rounds 12/14): both fetch-MLP levers (pred->LDS DMA, batched
// tg loads) were NEUTRAL-to-negative — input fetch is TLP-hidden at 8 blocks/CU.
// This is the lean round-11 state, the measured best (101.2us). Remaining time is
// harness poison fill (44us) + latency-bound sync-chain kernel (~35us): the
// structural floor for this decomposition.
__device__ __forceinline__ void st_wti(int* p, int v) {
    __hip_atomic_store(p, v, __ATOMIC_RELAXED, __HIP_MEMORY_SCOPE_AGENT);
}
__device__ __forceinline__ int ld_bpi(const int* p) {
    return __hip_atomic_load((int*)p, __ATOMIC_RELAXED, __HIP_MEMORY_SCOPE_AGENT);
}
__device__ __forceinline__ void st_wt(float* p, float v) {
    st_wti((int*)p, __float_as_int(v));
}
__device__ __forceinline__ float ld_bp(const float* p) {
    return __int_as_float(ld_bpi((const int*)p));
}
// 16B-wide L1+L2-bypass ops. "=&v" early-clobber: dest must not overlap the
// address pair. Results readable only after vm_wait0().
__device__ __forceinline__ f32x4 ld_bp4(const float* p) {
    f32x4 r;
    asm volatile("global_load_dwordx4 %0, %1, off sc0 sc1"
                 : "=&v"(r) : "v"(p) : "memory");
    return r;
}
__device__ __forceinline__ void st_wt4(float* p, f32x4 v) {
    asm volatile("global_store_dwordx4 %0, %1, off sc0 sc1"
                 :: "v"(p), "v"(v) : "memory");
}
__device__ __forceinline__ void vm_wait0() {
    asm volatile("s_waitcnt vmcnt(0)" ::: "memory");
    __builtin_amdgcn_sched_barrier(0);   // block reg-only hoisting past the wait
}

// Publish: drain this wave's write-through stores to MALL (vmcnt is wave-level,
// covers all 64 lanes), then bump the flag with a relaxed RMW.
__device__ __forceinline__ void flag_post(int* f, int lane) {
    asm volatile("s_waitcnt vmcnt(0)" ::: "memory");
    if (lane == 0)
        __hip_atomic_fetch_add(f, 1, __ATOMIC_RELAXED, __HIP_MEMORY_SCOPE_AGENT);
}
__device__ __forceinline__ void wait_flag(const int* f) {
    while (!__all(ld_bpi(f) != 0))
        __builtin_amdgcn_s_sleep(2);
    asm volatile("" ::: "memory");   // no payload reads hoisted above the spin
}
// wait until f[k] != 0 for all k in [k0, kend); kend-k0 <= 128
__device__ __forceinline__ void wait_flags_range(const int* f, int k0, int kend,
                                                 int lane) {
    if (k0 >= kend) return;
    for (;;) {
        int k1 = k0 + lane, k2 = k0 + 64 + lane;
        int v1 = (k1 < kend) ? ld_bpi(&f[k1]) : 1;
        int v2 = (k2 < kend) ? ld_bpi(&f[k2]) : 1;
        if (__all((v1 != 0) & (v2 != 0))) break;
        __builtin_amdgcn_s_sleep(2);
    }
    asm volatile("" ::: "memory");
}

// DPP move with INF fill (floats).
template<int CTRL, int RMASK>
__device__ __forceinline__ float dpp_mov_inf(float x) {
    return __int_as_float(__builtin_amdgcn_update_dpp(
        __float_as_int(INF_W), __float_as_int(x), CTRL, RMASK, 0xF, false));
}
template<int CTRL>
__device__ __forceinline__ int dpp_mov0_i(int x) {
    return __builtin_amdgcn_update_dpp(0, x, CTRL, 0xF, 0xF, true);
}

__device__ __forceinline__ float wave_prefix_min_incl(float t) {
    t = fminf(t, dpp_mov_inf<0x111,0xF>(t));
    t = fminf(t, dpp_mov_inf<0x112,0xF>(t));
    t = fminf(t, dpp_mov_inf<0x114,0xF>(t));
    t = fminf(t, dpp_mov_inf<0x118,0xF>(t));
    t = fminf(t, dpp_mov_inf<0x142,0xA>(t));
    t = fminf(t, dpp_mov_inf<0x143,0xC>(t));
    return t;
}

__device__ __forceinline__ void cummin_row(const float* jc, float* v) {
    float g[8];
#pragma unroll
    for (int i = 0; i < 8; ++i) g[i] = v[i] - jc[i];
    float c1[8];
    c1[0] = g[0];
#pragma unroll
    for (int i = 1; i < 8; ++i) c1[i] = fminf(g[i], g[i-1]);
    float c2[8];
    c2[0] = c1[0]; c2[1] = c1[1];
#pragma unroll
    for (int i = 2; i < 8; ++i) c2[i] = fminf(c1[i], c1[i-2]);
    float cj[8];
    cj[0] = c2[0]; cj[1] = c2[1]; cj[2] = c2[2]; cj[3] = c2[3];
#pragma unroll
    for (int i = 4; i < 8; ++i) cj[i] = fminf(c2[i], c2[i-4]);
    float t  = wave_prefix_min_incl(cj[7]);
    float ex = dpp_mov_inf<0x138,0xF>(t);
#pragma unroll
    for (int i = 0; i < 8; ++i) v[i] = jc[i] + fminf(cj[i], ex);
}

__device__ __forceinline__ void row_step(const float* jc, float* prev, const float* drow) {
    float lIn = dpp_mov_inf<0x138,0xF>(prev[7]);
    float rIn = dpp_mov_inf<0x130,0xF>(prev[0]);
    float m[8];
#pragma unroll
    for (int i = 0; i < 8; ++i) {
        float up = prev[i] + A_W;
        float ul = ((i == 0) ? lIn : prev[i-1]) + B_W;
        float ur = ((i == 7) ? rIn : prev[i+1]) + B_W;
        m[i] = fminf(fminf(drow[i], up), fminf(ul, ur));
    }
    cummin_row(jc, m);
#pragma unroll
    for (int i = 0; i < 8; ++i) prev[i] = m[i];
}

// 4 fused T3 steps (exact, INF outside grid). T3^4 == one call (TST==4).
__device__ __forceinline__ void t3x4(float* b) {
    float e[16];
#pragma unroll
    for (int k = 0; k < 4; ++k) e[k]    = dpp_mov_inf<0x138,0xF>(b[4+k]);
#pragma unroll
    for (int k = 0; k < 8; ++k) e[4+k]  = b[k];
#pragma unroll
    for (int k = 0; k < 4; ++k) e[12+k] = dpp_mov_inf<0x130,0xF>(b[k]);
    const float w0 = 4.f*A_W, w1 = 3.f*A_W + B_W, w2 = 2.f*A_W + 2.f*B_W;
    const float w3 = A_W + 3.f*B_W, w4 = 4.f*B_W;
#pragma unroll
    for (int i = 0; i < 8; ++i) {
        float m = e[i+4] + w0;
        m = fminf(m, fminf(e[i+3], e[i+5]) + w1);
        m = fminf(m, fminf(e[i+2], e[i+6]) + w2);
        m = fminf(m, fminf(e[i+1], e[i+7]) + w3);
        m = fminf(m, fminf(e[i+0], e[i+8]) + w4);
        b[i] = m;
    }
}

struct RowBits { int efg; int ebg; int rawbg; };

__device__ __forceinline__ RowBits make_rowbits(uint4 a, uint4 b) {
    int fg = ((a.x!=0u)?1:0) | ((a.y!=0u)?2:0) | ((a.z!=0u)?4:0) | ((a.w!=0u)?8:0)
           | ((b.x!=0u)?16:0) | ((b.y!=0u)?32:0) | ((b.z!=0u)?64:0) | ((b.w!=0u)?128:0);
    int bg = (~fg) & 0xFF;
    int lf = dpp_mov0_i<0x138>(fg), rf = dpp_mov0_i<0x130>(fg);
    int lb = dpp_mov0_i<0x138>(bg), rb = dpp_mov0_i<0x130>(bg);
    RowBits r;
    r.efg = (fg | (fg<<1) | (fg>>1) | ((lf>>7)&1) | ((rf&1)<<7)) & 0xFF;
    r.ebg = (bg | (bg<<1) | (bg>>1) | ((lb>>7)&1) | ((rb&1)<<7)) & 0xFF;
    r.rawbg = bg;
    return r;
}

__device__ __forceinline__ RowBits loadrow_bits(const int* tgb, int rr, int c0) {
    if (rr < 0 || rr >= HDIM) { RowBits z; z.efg = 0; z.ebg = 0; z.rawbg = 0; return z; }
    const uint4* p = (const uint4*)(tgb + (size_t)rr * WDIM + c0);
    return make_rowbits(p[0], p[1]);
}

// store max of an L row (prev[8] across wave) into mmax (write-through)
__device__ __forceinline__ void store_max(const float* prev, float* __restrict__ mmax,
                                          int idx, int lane) {
    float mx = prev[0];
#pragma unroll
    for (int i = 1; i < 8; ++i) mx = fmaxf(mx, prev[i]);
#pragma unroll
    for (int off = 32; off > 0; off >>= 1) mx = fmaxf(mx, __shfl_xor(mx, off));
    if (lane == 0) st_wt(&mmax[idx], mx);
}

// Exact boundary via chain walk over strips [k0, n-1]. Caller guarantees flags
// [k0, n-1] observed. 16B bypass loads issued before t3x4/cummin to hide MALL
// latency; results consumed only after vm_wait0().
__device__ __forceinline__ void chain_walk(const float* __restrict__ Lb, int k0, int n,
                                           const float* jc, int c0, float* prev) {
    float b[8];
    const float* Lr = Lb + (size_t)k0 * WDIM + c0;
    f32x4 l0 = ld_bp4(Lr);
    f32x4 l1 = ld_bp4(Lr + 4);
    vm_wait0();
#pragma unroll
    for (int i = 0; i < 4; ++i) { b[i] = l0[i]; b[4 + i] = l1[i]; }
    for (int sg = k0 + 1; sg < n; ++sg) {
        const float* Ls = Lb + (size_t)sg * WDIM + c0;
        f32x4 m0 = ld_bp4(Ls);
        f32x4 m1 = ld_bp4(Ls + 4);
        t3x4(b);                                 // T3^4 exact (TST==4)
        cummin_row(jc, b);
        vm_wait0();
#pragma unroll
        for (int i = 0; i < 4; ++i) {
            b[i]     = fminf(b[i],     m0[i]);
            b[4 + i] = fminf(b[4 + i], m1[i]);
        }
    }
#pragma unroll
    for (int i = 0; i < 8; ++i) prev[i] = b[i];
}

// k0 from ub = maxL[n-1]: keep strips with STRIP_COST*(n-1-k) <= ub (distances
// >= 0 make this sufficient; 1e-3 margin => rounding can only KEEP extra strips,
// never drop a tied one -> exact). g clamped to [0,127] defensively.
__device__ __forceinline__ int k0_from_ub(float ub, int n) {
    int g = (int)(ub * (1.0f / STRIP_COST) + 1e-3f);
    if (g < 0) g = 0;
    if (g > NSTRIP - 1) g = NSTRIP - 1;
    int k0 = n - 1 - g;
    return (k0 < 0) ? 0 : k0;
}

// =====================================================================================
// Fused kernel: all 3 strip phases + two-level final reduce in ONE dispatch.
// Co-residency by construction: __launch_bounds__(64,2) caps VGPR at 256; any
// VGPR<=256 gives >=2 waves/SIMD -> >=8 single-wave blocks/CU -> >=2048 slots =
// grid size (LDS 8KB -> 20/CU, not binding) => waits cannot deadlock (deps form
// a DAG over strips). (64,4) forbidden: VGPR->64, ~90MB scratch spill (round 3).
// =====================================================================================
__global__ __launch_bounds__(64, 2) void fused_kernel(
        const float* __restrict__ pred, const int* __restrict__ tg,
        const float* __restrict__ lv, float* __restrict__ out,
        float* __restrict__ Llast, float* __restrict__ mmax1, int* __restrict__ blkflags,
        float* __restrict__ Llast2, float* __restrict__ mmax2, float* __restrict__ sacc,
        int* f1, int* f2, int* f3, int* f4,
        float* __restrict__ sacc2, int* __restrict__ vv2) {
    const int s = blockIdx.x >> 7, sig = blockIdx.x & 127;
    const int lane = threadIdx.x;
    const int c0 = lane * 8;
    const int* tgb = tg + (size_t)s * NPIX;
    const int R0 = sig * TST;
    const int base = s * NSTRIP;
    float jc[8];
#pragma unroll
    for (int i = 0; i < 8; ++i) jc[i] = A_W * (float)(c0 + i);

    __shared__ float lds[TST][WDIM];   // 8 KB; single-wave block

    // ---------------- phase 1: local strip scan (INF incoming) -> Llast/mmax1/flags
    unsigned int smaskp = 0u, rawbgp = 0u;   // byte t = row t's 8-bit masks
    RowBits rA = loadrow_bits(tgb, R0 - 1, c0);
    RowBits rB = loadrow_bits(tgb, R0, c0);
    float prev[8];
#pragma unroll
    for (int i = 0; i < 8; ++i) prev[i] = INF_W;
    int fgor = 0, bgor = 0;
#pragma unroll
    for (int t = 0; t < TST; ++t) {
        RowBits rC = loadrow_bits(tgb, R0 + t + 1, c0);
        fgor |= (~rB.rawbg) & 0xFF;
        bgor |= rB.rawbg;
        int smask = (rA.efg | rB.efg | rC.efg) & (rA.ebg | rB.ebg | rC.ebg);
        smaskp |= ((unsigned int)smask) << (8 * t);
        rawbgp |= ((unsigned int)rB.rawbg) << (8 * t);
        float dr[8];
#pragma unroll
        for (int i = 0; i < 8; ++i) dr[i] = ((smask >> i) & 1) ? 0.f : INF_W;
        row_step(jc, prev, dr);
        rA = rB; rB = rC;
    }
    {
        float* Lr = Llast + ((size_t)base + sig) * WDIM + c0;
        f32x4 v0 = {prev[0], prev[1], prev[2], prev[3]};
        f32x4 v1 = {prev[4], prev[5], prev[6], prev[7]};
        st_wt4(Lr, v0);
        st_wt4(Lr + 4, v1);
        store_max(prev, mmax1, base + sig, lane);
        int wf = __any(fgor != 0) ? 1 : 0;
        int wb = __any(bgor != 0) ? 2 : 0;
        if (lane == 0) st_wti(&blkflags[blockIdx.x], wf | wb);
    }
    flag_post(&f1[base + sig], lane);

    // ---------------- phase 2: exact pass-1 rows -> LDS; flipped local scan -> Llast2/mmax2
    if (sig == 0) {
#pragma unroll
        for (int i = 0; i < 8; ++i) prev[i] = INF_W;
    } else {
        wait_flag(&f1[base + sig - 1]);
        float ub = ld_bp(&mmax1[base + sig - 1]);
        int k0 = k0_from_ub(ub, sig);
        wait_flags_range(f1 + base, k0, sig - 1, lane);
        chain_walk(Llast + (size_t)base * WDIM, k0, sig, jc, c0, prev);
    }
#pragma unroll
    for (int t = 0; t < TST; ++t) {
        unsigned int sm = (smaskp >> (8 * t)) & 0xFFu;
        float dr[8];
#pragma unroll
        for (int i = 0; i < 8; ++i) dr[i] = ((sm >> i) & 1u) ? 0.f : INF_W;
        row_step(jc, prev, dr);
        *(float4*)&lds[t][c0]     = make_float4(prev[0], prev[1], prev[2], prev[3]);
        *(float4*)&lds[t][c0 + 4] = make_float4(prev[4], prev[5], prev[6], prev[7]);
    }
    __syncthreads();
    // flipped (pass-2) local scan over this strip, INF incoming
#pragma unroll
    for (int i = 0; i < 8; ++i) prev[i] = INF_W;
#pragma unroll
    for (int t2 = 0; t2 < TST; ++t2) {
        float4 a = *(const float4*)&lds[TST - 1 - t2][504 - c0];
        float4 q = *(const float4*)&lds[TST - 1 - t2][508 - c0];
        float dr[8];
        dr[7]=a.x; dr[6]=a.y; dr[5]=a.z; dr[4]=a.w;
        dr[3]=q.x; dr[2]=q.y; dr[1]=q.z; dr[0]=q.w;
        row_step(jc, prev, dr);
    }
    const int sig2 = NSTRIP - 1 - sig;   // flipped strip index == this block's own rows
    {
        float* Lr = Llast2 + ((size_t)base + sig2) * WDIM + c0;
        f32x4 v0 = {prev[0], prev[1], prev[2], prev[3]};
        f32x4 v1 = {prev[4], prev[5], prev[6], prev[7]};
        st_wt4(Lr, v0);
        st_wt4(Lr + 4, v1);
        store_max(prev, mmax2, base + sig2, lane);
    }
    flag_post(&f2[base + sig2], lane);

    // ---------------- phase 3: exact pass-2 rows (dr from own LDS) + fused loss -> sacc
    if (sig2 == 0) {
#pragma unroll
        for (int i = 0; i < 8; ++i) prev[i] = INF_W;
    } else {
        wait_flag(&f2[base + sig2 - 1]);
        float ub = ld_bp(&mmax2[base + sig2 - 1]);
        int k0 = k0_from_ub(ub, sig2);
        wait_flags_range(f2 + base, k0, sig2 - 1, lane);
        chain_walk(Llast2 + (size_t)base * WDIM, k0, sig2, jc, c0, prev);
    }
    const size_t sb = (size_t)s * NPIX;
    float mx = 0.f, facc = 0.f, s1 = 0.f, s2 = 0.f, iacc = 0.f, pacc = 0.f;
#pragma unroll
    for (int t = 0; t < TST; ++t) {
        const int pr = R0 + (TST - 1) - t;        // == HDIM-1-(sig2*TST+t), own strip rows
        float4 a  = *(const float4*)&lds[TST - 1 - t][504 - c0];
        float4 b4 = *(const float4*)&lds[TST - 1 - t][508 - c0];
        float dr[8];
        dr[7]=a.x;  dr[6]=a.y;  dr[5]=a.z;  dr[4]=a.w;
        dr[3]=b4.x; dr[2]=b4.y; dr[1]=b4.z; dr[0]=b4.w;
        const size_t rbase = sb + (size_t)pr * WDIM + (WDIM - 8 - c0);
        float4 xa = *(const float4*)(pred + rbase);
        float4 xb = *(const float4*)(pred + rbase + 4);
        float px[8];
        px[7]=xa.x; px[6]=xa.y; px[5]=xa.z; px[4]=xa.w;
        px[3]=xb.x; px[2]=xb.y; px[1]=xb.z; px[0]=xb.w;
        // target bits for reversed columns: col 511-c0-i lives in lane 63-lane, bit 7-i
        int sh = __shfl((int)((rawbgp >> (8 * (TST - 1 - t))) & 0xFFu), 63 - lane);
        row_step(jc, prev, dr);
#pragma unroll
        for (int i = 0; i < 8; ++i) {
            float x = px[i];
            float dd = prev[i];
            float e = __expf(-fabsf(x));
            float inv = 1.f / (1.f + e);
            float pr_ = (x >= 0.f) ? inv : (1.f - inv);   // sigmoid(x)
            float L = __logf(1.f + e);                    // softplus(-|x|)
            bool t1 = ((sh >> (7 - i)) & 1) == 0;         // fg pixel
            float fo = t1 ? 0.25f * (1.f - pr_) * (1.f - pr_) * (fmaxf(-x, 0.f) + L)
                          : 0.75f * pr_ * pr_ * (fmaxf(x, 0.f) + L);
            facc += fo;
            float base_ = t1 ? (1.f - pr_) : pr_;
            s1 += base_;
            s2 += base_ * dd;
            float tf = t1 ? 1.f : 0.f;
            iacc += tf * pr_;
            pacc += pr_ + tf;
            mx = fmaxf(mx, dd);
        }
    }
#pragma unroll
    for (int off = 32; off > 0; off >>= 1) {
        facc += __shfl_xor(facc, off);
        s1   += __shfl_xor(s1, off);
        s2   += __shfl_xor(s2, off);
        iacc += __shfl_xor(iacc, off);
        pacc += __shfl_xor(pacc, off);
        mx    = fmaxf(mx, __shfl_xor(mx, off));
    }
    if (lane == 0) {
        const int idx = base + sig2;
        st_wt(&sacc[0 * NBLK + idx], s1);
        st_wt(&sacc[1 * NBLK + idx], s2);
        st_wt(&sacc[2 * NBLK + idx], iacc);
        st_wt(&sacc[3 * NBLK + idx], pacc);
        st_wt(&sacc[4 * NBLK + idx], mx);
        st_wt(&sacc[5 * NBLK + idx], facc);
    }
    flag_post(&f3[blockIdx.x], lane);

    // ---------------- phase 4a: per-sample reduce in each sample's sig==0 block
    if (sig != 0) return;
    wait_flags_range(f3, base, base + NSTRIP, lane);
    {
        int i0 = base + lane, i1 = i0 + 64;
        float t1 = ld_bp(&sacc[0 * NBLK + i0]) + ld_bp(&sacc[0 * NBLK + i1]);
        float t2 = ld_bp(&sacc[1 * NBLK + i0]) + ld_bp(&sacc[1 * NBLK + i1]);
        float ia = ld_bp(&sacc[2 * NBLK + i0]) + ld_bp(&sacc[2 * NBLK + i1]);
        float pa = ld_bp(&sacc[3 * NBLK + i0]) + ld_bp(&sacc[3 * NBLK + i1]);
        float mxs = fmaxf(ld_bp(&sacc[4 * NBLK + i0]), ld_bp(&sacc[4 * NBLK + i1]));
        float fa = ld_bp(&sacc[5 * NBLK + i0]) + ld_bp(&sacc[5 * NBLK + i1]);
        int   vv = ld_bpi(&blkflags[i0]) | ld_bpi(&blkflags[i1]);
#pragma unroll
        for (int off = 32; off > 0; off >>= 1) {
            t1 += __shfl_xor(t1, off);
            t2 += __shfl_xor(t2, off);
            ia += __shfl_xor(ia, off);
            pa += __shfl_xor(pa, off);
            fa += __shfl_xor(fa, off);
            mxs = fmaxf(mxs, __shfl_xor(mxs, off));
            vv |= __shfl_xor(vv, off);
        }
        if (lane == 0) {
            st_wt(&sacc2[0 * 16 + s], t1);
            st_wt(&sacc2[1 * 16 + s], t2);
            st_wt(&sacc2[2 * 16 + s], ia);
            st_wt(&sacc2[3 * 16 + s], pa);
            st_wt(&sacc2[4 * 16 + s], mxs);
            st_wt(&sacc2[5 * 16 + s], fa);
            st_wti(&vv2[s], vv);
        }
    }
    flag_post(&f4[s], lane);

    // ---------------- phase 4b: final combine in block 0 (16 lane-parallel samples)
    if (blockIdx.x != 0) return;
    for (;;) {
        int v = (lane < NSAMP) ? ld_bpi(&f4[lane]) : 1;
        if (__all(v != 0)) break;
        __builtin_amdgcn_s_sleep(2);
    }
    asm volatile("" ::: "memory");
    float fsum = 0.f, bsum = 0.f, dsum = 0.f, isum = 0.f;
    if (lane < NSAMP) {
        float t1  = ld_bp(&sacc2[0 * 16 + lane]);
        float t2  = ld_bp(&sacc2[1 * 16 + lane]);
        float ia  = ld_bp(&sacc2[2 * 16 + lane]);
        float pa  = ld_bp(&sacc2[3 * 16 + lane]);
        float mxs = ld_bp(&sacc2[4 * 16 + lane]);
        float fa  = ld_bp(&sacc2[5 * 16 + lane]);
        int   vv  = ld_bpi(&vv2[lane]);
        bool hasb = (vv & 3) == 3;     // boundary nonempty (has_fg && has_bg)
        fsum = fa;
        float distsum = hasb ? ((mxs > 0.f) ? t2 / fmaxf(mxs, 1e-12f) : 0.f) : t1;
        bsum = t1 + distsum;
        dsum = (2.f * ia + 1e-6f) / (pa + 1e-6f);
        isum = (ia + 1e-6f) / (pa - ia + 1e-6f);
    }
#pragma unroll
    for (int off = 32; off > 0; off >>= 1) {
        fsum += __shfl_xor(fsum, off);
        bsum += __shfl_xor(bsum, off);
        dsum += __shfl_xor(dsum, off);
        isum += __shfl_xor(isum, off);
    }
    if (lane == 0) {
        float focal = fsum / NTOT_F;
        float bnd   = bsum / NTOT_F;
        float dice = 1.f - dsum / 16.f;
        float iou  = 1.f - isum / 16.f;
        float l0 = lv[0], l1 = lv[1], l2 = lv[2], l3 = lv[3];
        float total = expf(-l0) * focal + l0 + expf(-l1) * dice + l1
                    + expf(-l2) * bnd  + l2 + expf(-l3) * iou  + l3;
        out[0] = total; out[1] = focal; out[2] = dice; out[3] = bnd; out[4] = iou;
    }
}

extern "C" void kernel_launch(void* const* d_in, const int* in_sizes, int n_in,
                              void* d_out, int out_size, void* d_ws, size_t ws_size,
                              hipStream_t stream) {
    const float* pred = (const float*)d_in[0];
    const int*   tg   = (const int*)d_in[1];
    const float* lv   = (const float*)d_in[2];
    float* out = (float*)d_out;
    char* ws = (char*)d_ws;
    int*   f1       = (int*)(ws + OFF_F1);
    int*   f2       = (int*)(ws + OFF_F2);
    int*   f3       = (int*)(ws + OFF_F3);
    int*   f4       = (int*)(ws + OFF_F4);
    int*   blkflags = (int*)(ws + OFF_FLAGS);
    float* sacc     = (float*)(ws + OFF_SACC);
    float* mmax1    = (float*)(ws + OFF_MMAX1);
    float* mmax2    = (float*)(ws + OFF_MMAX2);
    float* sacc2    = (float*)(ws + OFF_SACC2);
    int*   vv2      = (int*)(ws + OFF_VV2);
    float* Llast    = (float*)(ws + OFF_LLAST);
    float* Llast2   = (float*)(ws + OFF_LLAST2);

    // ws is poisoned between iterations -> flags (f1,f2,f3,f4) must be zeroed.
    hipMemsetAsync(ws, 0, 24704, stream);
    fused_kernel<<<NBLK, 64, 0, stream>>>(pred, tg, lv, out, Llast, mmax1, blkflags,
                                          Llast2, mmax2, sacc, f1, f2, f3, f4,
                                          sacc2, vv2);
}